// Round 6
// baseline (393.918 us; speedup 1.0000x reference)
//
#include <hip/hip_runtime.h>
#include <math.h>

// Problem constants
#define Bq 8
#define Nq 8192
#define Dq 256
#define Qq 4
#define Kq 2048
#define Mq (Nq / Qq)
#define TT (Bq * Nq)                    // 65536 tokens
#define QUANT_ELEMS ((size_t)TT * Dq)   // 16777216

#define CAP1Q 4096
#define THRESH 3e-4f        // fp16 margin band (~12 sigma of fp16-input score error)
#define CAND_MAX 16         // per-token candidate cap (overflow -> exact full scan)

// ws layout (bytes) — high-water 16,057,344 < 16 MiB (no overlays)
#define WS_CNT_OFF    0u
#define WS_LIST_OFF   1024u       // 4*4096 ints = 64 KB           -> ends   66560
#define WS_SX_OFF     66560u      // TT f32 = 256 KB               -> ends  328704
#define WS_PSC_OFF    328704u     // (unused this round)
#define WS_PCD_OFF    852992u     // (unused this round)
#define WS_ENH_OFF    1377280u    // 4 MB fp16 swizzled codes      -> ends 5571584
#define WS_ENP_OFF    5571584u    // 8 MB fp32 numpy-norm codes    -> ends 13960192
#define WS_PART_OFF   13960192u   // float4[2][TT] = 2 MB          -> ends 16057344

typedef __attribute__((ext_vector_type(8))) _Float16 f16x8;
typedef __attribute__((ext_vector_type(4))) _Float16 f16x4;
typedef __attribute__((ext_vector_type(4))) float    f32x4;

__device__ __forceinline__ void async_load16(const void* g, void* s) {
    __builtin_amdgcn_global_load_lds(
        (const __attribute__((address_space(1))) void*)g,
        (__attribute__((address_space(3))) void*)s, 16, 0, 0);
}

__device__ __forceinline__ float f32_div(float a, float b) {
    return (float)((double)a / (double)b);   // exact IEEE fp32 divide
}

// numpy pairwise norm of a 256-row, wave-parallel but BIT-EXACT vs the serial
// 8-accumulator + tree emulation (validated round 3). Lanes 0..15 active.
__device__ __forceinline__ float np_norm_wave(const float* __restrict__ src, int ln) {
#pragma clang fp contract(off)
    float r = 0.0f;
    if (ln < 16) {
        const float* p = src + (ln >> 3) * 128 + (ln & 7);
        #pragma unroll
        for (int m = 0; m < 16; ++m) { float v = p[m * 8]; r = r + v * v; }
    }
    float t = r + __shfl_xor(r, 1, 64);      // (r0+r1) ...
    t = t + __shfl_xor(t, 2, 64);            // (r0+r1)+(r2+r3) ...
    t = t + __shfl_xor(t, 4, 64);            // full 8-acc tree
    float b0 = __shfl(t, 0, 64);
    float b1 = __shfl(t, 8, 64);
    float n2 = b0 + b1;                      // pw(0:128) + pw(128:256)
    return fmaxf((float)sqrt((double)n2), 1e-12f);
}

// ---------------- prep: codes (fp16 swizzled + numpy fp32), x-norms, zeroing -
__global__ __launch_bounds__(256) void prep_kernel(const float* __restrict__ embed,
                                                   const float* __restrict__ x,
                                                   char* __restrict__ enh,
                                                   float* __restrict__ enp,
                                                   float* __restrict__ sxa,
                                                   int* __restrict__ cnt,
                                                   float* __restrict__ out) {
    if (blockIdx.x >= 2048) {
        // ---- x-norm branch (bit-exact mirror of the original in-gemm reduce) ----
        const int tid = threadIdx.x;
        const int qd  = tid & 3;
        const int row = (blockIdx.x - 2048) * 64 + (tid >> 2);
        const float* xr = x + (size_t)row * Dq + qd * 8;
        float s2 = 0.f;
        #pragma unroll
        for (int ch = 0; ch < 8; ++ch) {
            float4 u = *(const float4*)(xr + ch * 32);
            float4 v = *(const float4*)(xr + ch * 32 + 4);
            s2 += u.x * u.x + u.y * u.y + u.z * u.z + u.w * u.w;
            s2 += v.x * v.x + v.y * v.y + v.z * v.z + v.w * v.w;
        }
        s2 += __shfl_xor(s2, 1, 64);
        s2 += __shfl_xor(s2, 2, 64);
        float sxv = 1.0f / fmaxf(sqrtf(s2), 1e-12f);
        if (qd == 0) sxa[row] = sxv;
        return;
    }

    if (blockIdx.x == 0) {
        if (threadIdx.x < 4) cnt[threadIdx.x] = 0;
        if (threadIdx.x == 0) out[QUANT_ELEMS + TT] = 0.0f;   // vq_loss
    }

    int row = blockIdx.x * 4 + (threadIdx.x >> 6);   // 0..8191
    int ln  = threadIdx.x & 63;
    const float* src = embed + (size_t)row * Dq;

    // --- fp16 fast-normalized swizzled codes ---
    float4 v = *(const float4*)(src + ln * 4);
    float s = v.x * v.x + v.y * v.y + v.z * v.z + v.w * v.w;
    #pragma unroll
    for (int m = 1; m < 64; m <<= 1) s += __shfl_xor(s, m, 64);
    float sx = 1.0f / fmaxf(sqrtf(s), 1e-12f);
    int q = row >> 11, k = row & 2047, Tb = k >> 5, c = k & 31;
    int g = ln >> 1, h = ln & 1;
    f16x4 o;
    o[0] = (_Float16)(v.x * sx); o[1] = (_Float16)(v.y * sx);
    o[2] = (_Float16)(v.z * sx); o[3] = (_Float16)(v.w * sx);
    char* dst = enh + ((size_t)(q * 64 + Tb)) * 16384 + c * 512 + ((g ^ c) << 4) + h * 8;
    *(f16x4*)dst = o;

    // --- numpy-exact normalized fp32 codes ---
    float nm = np_norm_wave(src, ln);
    float* dstp = enp + (size_t)row * Dq;
    #pragma unroll
    for (int e = 0; e < 4; ++e) dstp[ln * 4 + e] = f32_div(src[ln * 4 + e], nm);
}

// ---------------- stage 1: LDS-shared-B fp16 MFMA scoring (round-5, proven) -
// grid 512: bid = (g<<1)|h ; block scores 256 tokens x 1024 codes (half h).
__global__ __launch_bounds__(256, 2) void gemm_kernel(const float* __restrict__ x,
                                                      const float* __restrict__ sxa,
                                                      const char* __restrict__ enh,
                                                      float4* __restrict__ part) {
    __shared__ __align__(16) char es[2][16384];

    const int tid = threadIdx.x;
    const int wv  = tid >> 6;
    const int ln  = tid & 63;
    const int qd  = ln >> 4;
    const int l15 = ln & 15;

    const int bid = blockIdx.x;              // 0..511
    const int h   = bid & 1;                 // codebook half
    const int g   = bid >> 1;                // 0..255 token-group
    const int b   = g >> 5;                  // batch 0..7
    const int rem = g & 31;
    const int q   = rem >> 3;                // quantizer 0..3
    const int m0  = (rem & 7) << 8;          // 256-token group within (b,q)
    const int t0  = b * Nq + q * Mq + m0;
    const int t0w = t0 + wv * 64;

    // prologue: load x with precomputed 1/norm (bit-exact, r3-validated)
    f16x8 ah[4][8];
    #pragma unroll
    for (int mf = 0; mf < 4; ++mf) {
        const int tok = t0w + mf * 16 + l15;
        const float sxv = sxa[tok];
        const float* xr = x + (size_t)tok * Dq + qd * 8;
        #pragma unroll
        for (int ch = 0; ch < 8; ++ch) {
            float4 u = *(const float4*)(xr + ch * 32);
            float4 v = *(const float4*)(xr + ch * 32 + 4);
            f16x8 f;
            f[0] = (_Float16)(u.x * sxv); f[1] = (_Float16)(u.y * sxv);
            f[2] = (_Float16)(u.z * sxv); f[3] = (_Float16)(u.w * sxv);
            f[4] = (_Float16)(v.x * sxv); f[5] = (_Float16)(v.y * sxv);
            f[6] = (_Float16)(v.z * sxv); f[7] = (_Float16)(v.w * sxv);
            ah[mf][ch] = f;
        }
    }

    float b1[4][4], b2[4][4];
    int   ic[4][4];
    #pragma unroll
    for (int mf = 0; mf < 4; ++mf)
        #pragma unroll
        for (int r = 0; r < 4; ++r) { b1[mf][r] = -2.0f; b2[mf][r] = -2.0f; ic[mf][r] = 0; }

    const char* ebase = enh + ((size_t)(q * 64 + h * 32)) * 16384;

    #pragma unroll
    for (int i = 0; i < 4; ++i) {
        int off = i * 4096 + wv * 1024 + ln * 16;
        async_load16(ebase + off, es[0] + off);
    }
    __syncthreads();

    for (int T = 0; T < 32; ++T) {
        if (T + 1 < 32) {
            const char* src = ebase + (size_t)(T + 1) * 16384;
            #pragma unroll
            for (int i = 0; i < 4; ++i) {
                int off = i * 4096 + wv * 1024 + ln * 16;
                async_load16(src + off, es[(T + 1) & 1] + off);
            }
        }
        const char* esb = es[T & 1];

        #pragma unroll
        for (int s = 0; s < 2; ++s) {
            const int  c  = s * 16 + l15;
            const char* cb = esb + c * 512;
            f16x8 bfr[8];
            #pragma unroll
            for (int ch = 0; ch < 8; ++ch)
                bfr[ch] = *(const f16x8*)(cb + ((((ch << 2) | qd) ^ c) << 4));

            f32x4 a[4];
            #pragma unroll
            for (int mf = 0; mf < 4; ++mf) a[mf] = (f32x4){0.f, 0.f, 0.f, 0.f};
            #pragma unroll
            for (int ch = 0; ch < 8; ++ch) {
                #pragma unroll
                for (int mf = 0; mf < 4; ++mf)
                    a[mf] = __builtin_amdgcn_mfma_f32_16x16x32_f16(ah[mf][ch], bfr[ch], a[mf], 0, 0, 0);
            }

            const int cg = (h << 10) | (T << 5) | (s << 4) | l15;
            #pragma unroll
            for (int mf = 0; mf < 4; ++mf)
                #pragma unroll
                for (int r = 0; r < 4; ++r) {
                    // exact top-2 update: cmp, med3, max, cndmask. invariant
                    // b1>=b2; med3(s,b1,b2) is precisely the new 2nd-best;
                    // strict > keeps the earliest (smallest) index on fp ties.
                    float sv = a[mf][r];
                    bool  gt = sv > b1[mf][r];
                    b2[mf][r] = __builtin_amdgcn_fmed3f(sv, b1[mf][r], b2[mf][r]);
                    b1[mf][r] = fmaxf(b1[mf][r], sv);
                    ic[mf][r] = gt ? cg : ic[mf][r];
                }
        }
        __syncthreads();
    }

    float fb1[4][4], fb2[4][4];
    int   fic[4][4];
    #pragma unroll
    for (int mf = 0; mf < 4; ++mf)
        #pragma unroll
        for (int r = 0; r < 4; ++r) {
            float v1 = b1[mf][r], v2 = b2[mf][r]; int vi = ic[mf][r];
            #pragma unroll
            for (int m = 1; m < 16; m <<= 1) {
                float o1 = __shfl_xor(v1, m, 64);
                float o2 = __shfl_xor(v2, m, 64);
                int   oi = __shfl_xor(vi, m, 64);
                if (o1 > v1 || (o1 == v1 && oi < vi)) { v2 = fmaxf(v1, o2); v1 = o1; vi = oi; }
                else v2 = fmaxf(v2, o1);
            }
            fb1[mf][r] = v1; fb2[mf][r] = v2; fic[mf][r] = vi;
        }

    if (l15 == 0) {
        #pragma unroll
        for (int mf = 0; mf < 4; ++mf)
            #pragma unroll
            for (int r = 0; r < 4; ++r) {
                int t = t0w + mf * 16 + qd * 4 + r;
                float4 pv;
                pv.x = fb1[mf][r];
                pv.y = fb2[mf][r];
                pv.z = __int_as_float(fic[mf][r]);
                pv.w = 0.f;
                part[(size_t)h * TT + t] = pv;
            }
    }
}

// ---------------- stage 1b: merge halves, encoding + list + gather-write ----
__global__ __launch_bounds__(256) void merge_kernel(const float* __restrict__ embed,
                                                    const float4* __restrict__ part,
                                                    float* __restrict__ out,
                                                    int* __restrict__ cnt,
                                                    int* __restrict__ list) {
    const int wv = threadIdx.x >> 6, ln = threadIdx.x & 63;
    const int nw = gridDim.x * 4;

    for (int t = blockIdx.x * 4 + wv; t < TT; t += nw) {
        float4 pa = part[t];          // half 0 (codes    0..1023)
        float4 pb = part[TT + t];     // half 1 (codes 1024..2047)
        // exact sorted-merge of two top-2 lists; tie -> half 0 (smaller index)
        float v1, v2; int vi;
        if (pb.x > pa.x) { v1 = pb.x; vi = __float_as_int(pb.z); v2 = fmaxf(pa.x, pb.y); }
        else             { v1 = pa.x; vi = __float_as_int(pa.z); v2 = fmaxf(pb.x, pa.y); }
        const int q = (t >> 11) & 3;

        if (ln == 0) {
            out[QUANT_ELEMS + (size_t)t] = (float)vi;
            if (v1 - v2 < THRESH) {
                int pos = atomicAdd(&cnt[q], 1);
                if (pos < CAP1Q) list[q * CAP1Q + pos] = t;
            }
        }
        const float* er = embed + ((size_t)(q * Kq + vi)) * Dq;
        float4 v = *(const float4*)(er + ln * 4);
        *(float4*)(out + (size_t)t * Dq + ln * 4) = v;
    }
}

// ---------------- stage 2: candidate collection + exact eval ----------------
// Per 64 marginal tokens: re-run the fp16 MFMA scoring (bit-identical to gemm
// by construction) over all 2048 codes, collect codes with s >= v1 - THRESH
// (exact argmax provably inside, same 12-sigma bound as THRESH itself), then
// numpy-exact evaluate only those few candidates. Overflow -> full exact scan.
__global__ __launch_bounds__(256) void cand_kernel(const float* __restrict__ x,
                                                   const float* __restrict__ sxa,
                                                   const char* __restrict__ enh,
                                                   const float* __restrict__ enp,
                                                   const float4* __restrict__ part,
                                                   const float* __restrict__ embed,
                                                   const int* __restrict__ cnt,
                                                   const int* __restrict__ list,
                                                   float* __restrict__ out) {
#pragma clang fp contract(off)
    __shared__ __align__(16) char es[2][16384];     // enh dbuf; reused as xn scratch
    __shared__ int   stok[64];
    __shared__ float sv1[64];
    __shared__ int   scnt[64];
    __shared__ unsigned short scand[64][CAND_MAX];

    const int tid = threadIdx.x;
    const int wv  = tid >> 6;
    const int ln  = tid & 63;
    const int qd  = ln >> 4;
    const int l15 = ln & 15;

    int cq[4], nbq[4], total = 0;
    #pragma unroll
    for (int q = 0; q < 4; ++q) {
        int c = cnt[q]; if (c > CAP1Q) c = CAP1Q;
        cq[q] = c; nbq[q] = (c + 63) >> 6; total += nbq[q];
    }

    for (int j = blockIdx.x; j < total; j += gridDim.x) {
        int rem = j, q = 0;
        while (rem >= nbq[q]) { rem -= nbq[q]; ++q; }
        const int base = rem << 6;

        if (tid < 64) {
            int idx = base + tid;
            int tok = list[q * CAP1Q + (idx < cq[q] ? idx : base)];   // pad = dup
            stok[tid] = tok;
            scnt[tid] = 0;
            sv1[tid]  = fmaxf(part[tok].x, part[TT + tok].x);         // merged fp16 max
        }
        __syncthreads();

        // A-fragment for this wave's 16 tokens (identical construction to gemm)
        f16x8 ah[8];
        {
            const int tok = stok[wv * 16 + l15];
            const float sxv = sxa[tok];
            const float* xr = x + (size_t)tok * Dq + qd * 8;
            #pragma unroll
            for (int ch = 0; ch < 8; ++ch) {
                float4 u = *(const float4*)(xr + ch * 32);
                float4 v = *(const float4*)(xr + ch * 32 + 4);
                f16x8 f;
                f[0] = (_Float16)(u.x * sxv); f[1] = (_Float16)(u.y * sxv);
                f[2] = (_Float16)(u.z * sxv); f[3] = (_Float16)(u.w * sxv);
                f[4] = (_Float16)(v.x * sxv); f[5] = (_Float16)(v.y * sxv);
                f[6] = (_Float16)(v.z * sxv); f[7] = (_Float16)(v.w * sxv);
                ah[ch] = f;
            }
        }
        float thr[4];
        #pragma unroll
        for (int r = 0; r < 4; ++r) thr[r] = sv1[wv * 16 + qd * 4 + r] - THRESH;

        const char* ebase = enh + ((size_t)(q * 64)) * 16384;   // full codebook q
        #pragma unroll
        for (int i = 0; i < 4; ++i) {
            int off = i * 4096 + wv * 1024 + ln * 16;
            async_load16(ebase + off, es[0] + off);
        }
        __syncthreads();

        for (int T = 0; T < 64; ++T) {
            if (T + 1 < 64) {
                const char* src = ebase + (size_t)(T + 1) * 16384;
                #pragma unroll
                for (int i = 0; i < 4; ++i) {
                    int off = i * 4096 + wv * 1024 + ln * 16;
                    async_load16(src + off, es[(T + 1) & 1] + off);
                }
            }
            const char* esb = es[T & 1];

            #pragma unroll
            for (int s = 0; s < 2; ++s) {
                const int  c  = s * 16 + l15;
                const char* cb = esb + c * 512;
                f16x8 bfr[8];
                #pragma unroll
                for (int ch = 0; ch < 8; ++ch)
                    bfr[ch] = *(const f16x8*)(cb + ((((ch << 2) | qd) ^ c) << 4));

                f32x4 a = {0.f, 0.f, 0.f, 0.f};
                #pragma unroll
                for (int ch = 0; ch < 8; ++ch)
                    a = __builtin_amdgcn_mfma_f32_16x16x32_f16(ah[ch], bfr[ch], a, 0, 0, 0);

                const int cg = (T << 5) | (s << 4) | l15;   // global code 0..2047
                #pragma unroll
                for (int r = 0; r < 4; ++r) {
                    if (a[r] >= thr[r]) {
                        int slot = wv * 16 + qd * 4 + r;
                        int pos = atomicAdd(&scnt[slot], 1);
                        if (pos < CAND_MAX) scand[slot][pos] = (unsigned short)cg;
                    }
                }
            }
            __syncthreads();
        }

        // ---- exact eval of candidates (numpy-bit-exact, lifted from fix_partial)
        float* xnw = (float*)(es[0] + wv * 4096);   // 1 KB scratch per wave
        for (int i = 0; i < 16; ++i) {
            const int slot = wv * 16 + i;
            const int tok  = stok[slot];
            const float* xr = x + (size_t)tok * Dq;
            float nm = np_norm_wave(xr, ln);
            #pragma unroll
            for (int e = 0; e < 4; ++e)
                xnw[ln * 4 + e] = f32_div(xr[ln * 4 + e], nm);
            __syncthreads();   // uniform: all waves run 16 iterations

            const int ncand = scnt[slot];
            float bs = -2.0f; int bc = 0x7fffffff;
            if (ncand <= CAND_MAX) {
                if (ln < ncand) {
                    int code = scand[slot][ln];
                    const float* er2 = enp + ((size_t)(q * Kq + code)) * Dq;
                    float l0 = 0.f, l1 = 0.f, l2 = 0.f, l3 = 0.f;
                    for (int d = 0; d < Dq; d += 4) {
                        float4 e = *(const float4*)(er2 + d);
                        float4 xv = *(const float4*)&xnw[d];
                        l0 = l0 + xv.x * e.x; l1 = l1 + xv.y * e.y;
                        l2 = l2 + xv.z * e.z; l3 = l3 + xv.w * e.w;
                    }
                    bs = (l0 + l1) + (l2 + l3);   // numpy SSE tree
                    bc = code;
                }
            } else {
                // overflow fallback: full exact scan, 32 codes/lane
                for (int k = 0; k < 32; ++k) {
                    int code = k * 64 + ln;
                    const float* er2 = enp + ((size_t)(q * Kq + code)) * Dq;
                    float l0 = 0.f, l1 = 0.f, l2 = 0.f, l3 = 0.f;
                    for (int d = 0; d < Dq; d += 4) {
                        float4 e = *(const float4*)(er2 + d);
                        float4 xv = *(const float4*)&xnw[d];
                        l0 = l0 + xv.x * e.x; l1 = l1 + xv.y * e.y;
                        l2 = l2 + xv.z * e.z; l3 = l3 + xv.w * e.w;
                    }
                    float sE = (l0 + l1) + (l2 + l3);
                    if (sE > bs || (sE == bs && code < bc)) { bs = sE; bc = code; }
                }
            }
            // wave argmax reduce (exact score desc, code asc on ties)
            #pragma unroll
            for (int m = 1; m < 64; m <<= 1) {
                float os = __shfl_xor(bs, m, 64);
                int   oc = __shfl_xor(bc, m, 64);
                if (os > bs || (os == bs && oc < bc)) { bs = os; bc = oc; }
            }
            if (ln == 0) out[QUANT_ELEMS + (size_t)tok] = (float)bc;
            const float* er = embed + ((size_t)(q * Kq + bc)) * Dq;
            float4 v = *(const float4*)(er + ln * 4);
            *(float4*)(out + (size_t)tok * Dq + ln * 4) = v;
            __syncthreads();   // xnw reused next i
        }
        __syncthreads();       // es reused next j
    }
}

extern "C" void kernel_launch(void* const* d_in, const int* in_sizes, int n_in,
                              void* d_out, int out_size, void* d_ws, size_t ws_size,
                              hipStream_t stream) {
    const float* x     = (const float*)d_in[0];
    const float* embed = (const float*)d_in[1];
    float* out = (float*)d_out;
    char*  ws  = (char*)d_ws;
    int*    cnt    = (int*)(ws + WS_CNT_OFF);
    int*    list   = (int*)(ws + WS_LIST_OFF);
    float*  sxa    = (float*)(ws + WS_SX_OFF);
    char*   enh    = ws + WS_ENH_OFF;
    float*  enp    = (float*)(ws + WS_ENP_OFF);
    float4* part   = (float4*)(ws + WS_PART_OFF);

    prep_kernel<<<3072, 256, 0, stream>>>(embed, x, enh, enp, sxa, cnt, out);
    gemm_kernel<<<512, 256, 0, stream>>>(x, sxa, enh, part);
    merge_kernel<<<2048, 256, 0, stream>>>(embed, part, out, cnt, list);
    cand_kernel<<<256, 256, 0, stream>>>(x, sxa, enh, enp, part, embed, cnt, list, out);
}

// Round 7
// 275.748 us; speedup vs baseline: 1.4285x; 1.4285x over previous
//
#include <hip/hip_runtime.h>
#include <math.h>

// Problem constants
#define Bq 8
#define Nq 8192
#define Dq 256
#define Qq 4
#define Kq 2048
#define Mq (Nq / Qq)
#define TT (Bq * Nq)                    // 65536 tokens
#define QUANT_ELEMS ((size_t)TT * Dq)   // 16777216

#define CAP1Q 4096
#define THRESH 3e-4f        // fp16 margin band (~12 sigma of fp16-input score error)
#define CAND_MAX 16         // per-token candidate cap (overflow -> exact full scan)

// ws layout (bytes) — high-water 16,057,344 < 16 MiB
#define WS_CNT_OFF    0u
#define WS_LIST_OFF   1024u       // 4*4096 ints = 64 KB           -> ends   66560
#define WS_SX_OFF     66560u      // TT f32 = 256 KB               -> ends  328704
#define WS_ENH_OFF    1377280u    // 4 MB fp16 swizzled codes      -> ends 5571584
#define WS_ENP_OFF    5571584u    // 8 MB fp32 numpy-norm codes    -> ends 13960192
#define WS_PART_OFF   13960192u   // float4[2][TT] = 2 MB          -> ends 16057344

typedef __attribute__((ext_vector_type(8))) _Float16 f16x8;
typedef __attribute__((ext_vector_type(4))) _Float16 f16x4;
typedef __attribute__((ext_vector_type(4))) float    f32x4;

__device__ __forceinline__ void async_load16(const void* g, void* s) {
    __builtin_amdgcn_global_load_lds(
        (const __attribute__((address_space(1))) void*)g,
        (__attribute__((address_space(3))) void*)s, 16, 0, 0);
}

__device__ __forceinline__ float f32_div(float a, float b) {
    return (float)((double)a / (double)b);   // exact IEEE fp32 divide
}

// numpy pairwise norm of a 256-row, wave-parallel but BIT-EXACT vs the serial
// 8-accumulator + tree emulation (validated round 3). Lanes 0..15 active.
__device__ __forceinline__ float np_norm_wave(const float* __restrict__ src, int ln) {
#pragma clang fp contract(off)
    float r = 0.0f;
    if (ln < 16) {
        const float* p = src + (ln >> 3) * 128 + (ln & 7);
        #pragma unroll
        for (int m = 0; m < 16; ++m) { float v = p[m * 8]; r = r + v * v; }
    }
    float t = r + __shfl_xor(r, 1, 64);      // (r0+r1) ...
    t = t + __shfl_xor(t, 2, 64);            // (r0+r1)+(r2+r3) ...
    t = t + __shfl_xor(t, 4, 64);            // full 8-acc tree
    float b0 = __shfl(t, 0, 64);
    float b1 = __shfl(t, 8, 64);
    float n2 = b0 + b1;                      // pw(0:128) + pw(128:256)
    return fmaxf((float)sqrt((double)n2), 1e-12f);
}

// ---------------- prep: codes (fp16 swizzled + numpy fp32), x-norms, zeroing -
__global__ __launch_bounds__(256) void prep_kernel(const float* __restrict__ embed,
                                                   const float* __restrict__ x,
                                                   char* __restrict__ enh,
                                                   float* __restrict__ enp,
                                                   float* __restrict__ sxa,
                                                   int* __restrict__ cnt,
                                                   float* __restrict__ out) {
    if (blockIdx.x >= 2048) {
        // ---- x-norm branch (bit-exact mirror of the original in-gemm reduce) ----
        const int tid = threadIdx.x;
        const int qd  = tid & 3;
        const int row = (blockIdx.x - 2048) * 64 + (tid >> 2);
        const float* xr = x + (size_t)row * Dq + qd * 8;
        float s2 = 0.f;
        #pragma unroll
        for (int ch = 0; ch < 8; ++ch) {
            float4 u = *(const float4*)(xr + ch * 32);
            float4 v = *(const float4*)(xr + ch * 32 + 4);
            s2 += u.x * u.x + u.y * u.y + u.z * u.z + u.w * u.w;
            s2 += v.x * v.x + v.y * v.y + v.z * v.z + v.w * v.w;
        }
        s2 += __shfl_xor(s2, 1, 64);
        s2 += __shfl_xor(s2, 2, 64);
        float sxv = 1.0f / fmaxf(sqrtf(s2), 1e-12f);
        if (qd == 0) sxa[row] = sxv;
        return;
    }

    if (blockIdx.x == 0) {
        if (threadIdx.x < 4) cnt[threadIdx.x] = 0;
        if (threadIdx.x == 0) out[QUANT_ELEMS + TT] = 0.0f;   // vq_loss
    }

    int row = blockIdx.x * 4 + (threadIdx.x >> 6);   // 0..8191
    int ln  = threadIdx.x & 63;
    const float* src = embed + (size_t)row * Dq;

    // --- fp16 fast-normalized swizzled codes ---
    float4 v = *(const float4*)(src + ln * 4);
    float s = v.x * v.x + v.y * v.y + v.z * v.z + v.w * v.w;
    #pragma unroll
    for (int m = 1; m < 64; m <<= 1) s += __shfl_xor(s, m, 64);
    float sx = 1.0f / fmaxf(sqrtf(s), 1e-12f);
    int q = row >> 11, k = row & 2047, Tb = k >> 5, c = k & 31;
    int g = ln >> 1, h = ln & 1;
    f16x4 o;
    o[0] = (_Float16)(v.x * sx); o[1] = (_Float16)(v.y * sx);
    o[2] = (_Float16)(v.z * sx); o[3] = (_Float16)(v.w * sx);
    char* dst = enh + ((size_t)(q * 64 + Tb)) * 16384 + c * 512 + ((g ^ c) << 4) + h * 8;
    *(f16x4*)dst = o;

    // --- numpy-exact normalized fp32 codes ---
    float nm = np_norm_wave(src, ln);
    float* dstp = enp + (size_t)row * Dq;
    #pragma unroll
    for (int e = 0; e < 4; ++e) dstp[ln * 4 + e] = f32_div(src[ln * 4 + e], nm);
}

// ---------------- stage 1: LDS-shared-B fp16 MFMA scoring (round-5, proven) -
// grid 512: bid = (g<<1)|h ; block scores 256 tokens x 1024 codes (half h).
__global__ __launch_bounds__(256, 2) void gemm_kernel(const float* __restrict__ x,
                                                      const float* __restrict__ sxa,
                                                      const char* __restrict__ enh,
                                                      float4* __restrict__ part) {
    __shared__ __align__(16) char es[2][16384];

    const int tid = threadIdx.x;
    const int wv  = tid >> 6;
    const int ln  = tid & 63;
    const int qd  = ln >> 4;
    const int l15 = ln & 15;

    const int bid = blockIdx.x;              // 0..511
    const int h   = bid & 1;                 // codebook half
    const int g   = bid >> 1;                // 0..255 token-group
    const int b   = g >> 5;                  // batch 0..7
    const int rem = g & 31;
    const int q   = rem >> 3;                // quantizer 0..3
    const int m0  = (rem & 7) << 8;          // 256-token group within (b,q)
    const int t0  = b * Nq + q * Mq + m0;
    const int t0w = t0 + wv * 64;

    // prologue: load x with precomputed 1/norm (bit-exact, r3-validated)
    f16x8 ah[4][8];
    #pragma unroll
    for (int mf = 0; mf < 4; ++mf) {
        const int tok = t0w + mf * 16 + l15;
        const float sxv = sxa[tok];
        const float* xr = x + (size_t)tok * Dq + qd * 8;
        #pragma unroll
        for (int ch = 0; ch < 8; ++ch) {
            float4 u = *(const float4*)(xr + ch * 32);
            float4 v = *(const float4*)(xr + ch * 32 + 4);
            f16x8 f;
            f[0] = (_Float16)(u.x * sxv); f[1] = (_Float16)(u.y * sxv);
            f[2] = (_Float16)(u.z * sxv); f[3] = (_Float16)(u.w * sxv);
            f[4] = (_Float16)(v.x * sxv); f[5] = (_Float16)(v.y * sxv);
            f[6] = (_Float16)(v.z * sxv); f[7] = (_Float16)(v.w * sxv);
            ah[mf][ch] = f;
        }
    }

    float b1[4][4], b2[4][4];
    int   ic[4][4];
    #pragma unroll
    for (int mf = 0; mf < 4; ++mf)
        #pragma unroll
        for (int r = 0; r < 4; ++r) { b1[mf][r] = -2.0f; b2[mf][r] = -2.0f; ic[mf][r] = 0; }

    const char* ebase = enh + ((size_t)(q * 64 + h * 32)) * 16384;

    #pragma unroll
    for (int i = 0; i < 4; ++i) {
        int off = i * 4096 + wv * 1024 + ln * 16;
        async_load16(ebase + off, es[0] + off);
    }
    __syncthreads();

    for (int T = 0; T < 32; ++T) {
        if (T + 1 < 32) {
            const char* src = ebase + (size_t)(T + 1) * 16384;
            #pragma unroll
            for (int i = 0; i < 4; ++i) {
                int off = i * 4096 + wv * 1024 + ln * 16;
                async_load16(src + off, es[(T + 1) & 1] + off);
            }
        }
        const char* esb = es[T & 1];

        #pragma unroll
        for (int s = 0; s < 2; ++s) {
            const int  c  = s * 16 + l15;
            const char* cb = esb + c * 512;
            f16x8 bfr[8];
            #pragma unroll
            for (int ch = 0; ch < 8; ++ch)
                bfr[ch] = *(const f16x8*)(cb + ((((ch << 2) | qd) ^ c) << 4));

            f32x4 a[4];
            #pragma unroll
            for (int mf = 0; mf < 4; ++mf) a[mf] = (f32x4){0.f, 0.f, 0.f, 0.f};
            #pragma unroll
            for (int ch = 0; ch < 8; ++ch) {
                #pragma unroll
                for (int mf = 0; mf < 4; ++mf)
                    a[mf] = __builtin_amdgcn_mfma_f32_16x16x32_f16(ah[mf][ch], bfr[ch], a[mf], 0, 0, 0);
            }

            const int cg = (h << 10) | (T << 5) | (s << 4) | l15;
            #pragma unroll
            for (int mf = 0; mf < 4; ++mf)
                #pragma unroll
                for (int r = 0; r < 4; ++r) {
                    // exact top-2 update: cmp, med3, max, cndmask. invariant
                    // b1>=b2; med3(s,b1,b2) is precisely the new 2nd-best;
                    // strict > keeps the earliest (smallest) index on fp ties.
                    float sv = a[mf][r];
                    bool  gt = sv > b1[mf][r];
                    b2[mf][r] = __builtin_amdgcn_fmed3f(sv, b1[mf][r], b2[mf][r]);
                    b1[mf][r] = fmaxf(b1[mf][r], sv);
                    ic[mf][r] = gt ? cg : ic[mf][r];
                }
        }
        __syncthreads();
    }

    float fb1[4][4], fb2[4][4];
    int   fic[4][4];
    #pragma unroll
    for (int mf = 0; mf < 4; ++mf)
        #pragma unroll
        for (int r = 0; r < 4; ++r) {
            float v1 = b1[mf][r], v2 = b2[mf][r]; int vi = ic[mf][r];
            #pragma unroll
            for (int m = 1; m < 16; m <<= 1) {
                float o1 = __shfl_xor(v1, m, 64);
                float o2 = __shfl_xor(v2, m, 64);
                int   oi = __shfl_xor(vi, m, 64);
                if (o1 > v1 || (o1 == v1 && oi < vi)) { v2 = fmaxf(v1, o2); v1 = o1; vi = oi; }
                else v2 = fmaxf(v2, o1);
            }
            fb1[mf][r] = v1; fb2[mf][r] = v2; fic[mf][r] = vi;
        }

    if (l15 == 0) {
        #pragma unroll
        for (int mf = 0; mf < 4; ++mf)
            #pragma unroll
            for (int r = 0; r < 4; ++r) {
                int t = t0w + mf * 16 + qd * 4 + r;
                float4 pv;
                pv.x = fb1[mf][r];
                pv.y = fb2[mf][r];
                pv.z = __int_as_float(fic[mf][r]);
                pv.w = 0.f;
                part[(size_t)h * TT + t] = pv;
            }
    }
}

// ---------------- stage 1b: merge halves, encoding + list + gather-write ----
__global__ __launch_bounds__(256) void merge_kernel(const float* __restrict__ embed,
                                                    const float4* __restrict__ part,
                                                    float* __restrict__ out,
                                                    int* __restrict__ cnt,
                                                    int* __restrict__ list) {
    const int wv = threadIdx.x >> 6, ln = threadIdx.x & 63;
    const int nw = gridDim.x * 4;

    for (int t = blockIdx.x * 4 + wv; t < TT; t += nw) {
        float4 pa = part[t];          // half 0 (codes    0..1023)
        float4 pb = part[TT + t];     // half 1 (codes 1024..2047)
        // exact sorted-merge of two top-2 lists; tie -> half 0 (smaller index)
        float v1, v2; int vi;
        if (pb.x > pa.x) { v1 = pb.x; vi = __float_as_int(pb.z); v2 = fmaxf(pa.x, pb.y); }
        else             { v1 = pa.x; vi = __float_as_int(pa.z); v2 = fmaxf(pb.x, pa.y); }
        const int q = (t >> 11) & 3;

        if (ln == 0) {
            out[QUANT_ELEMS + (size_t)t] = (float)vi;
            if (v1 - v2 < THRESH) {
                int pos = atomicAdd(&cnt[q], 1);
                if (pos < CAP1Q) list[q * CAP1Q + pos] = t;
            }
        }
        const float* er = embed + ((size_t)(q * Kq + vi)) * Dq;
        float4 v = *(const float4*)(er + ln * 4);
        *(float4*)(out + (size_t)t * Dq + ln * 4) = v;
    }
}

// ---------------- stage 2: parallel candidate scan + exact eval -------------
// Item = 16 marginal tokens. All 4 waves share the item's tokens (identical
// A-fragments); wave w scans codebook quarter w reading B-fragments straight
// from L2-resident enh (no LDS staging, no per-tile barrier). Candidates
// (fp16 score >= v1 - THRESH; exact argmax provably inside, r5/r6-validated
// bound) go to shared lists; then 256 threads = 16 tokens x 16 slots do the
// numpy-exact dots in parallel. Overflow (>16 cands, ~never) -> exact full scan.
__global__ __launch_bounds__(256) void cand_kernel(const float* __restrict__ x,
                                                   const float* __restrict__ sxa,
                                                   const char* __restrict__ enh,
                                                   const float* __restrict__ enp,
                                                   const float4* __restrict__ part,
                                                   const float* __restrict__ embed,
                                                   const int* __restrict__ cnt,
                                                   const int* __restrict__ list,
                                                   float* __restrict__ out) {
#pragma clang fp contract(off)
    __shared__ float xn[16][Dq];                 // numpy-normalized x rows (16 KB)
    __shared__ int   stok[16];
    __shared__ float sv1[16];
    __shared__ int   scnt[16];
    __shared__ unsigned short scand[16][CAND_MAX];
    __shared__ float sc_s[256];
    __shared__ int   sc_c[256];
    __shared__ int   fbc[16];

    const int tid = threadIdx.x;
    const int wv  = tid >> 6;
    const int ln  = tid & 63;
    const int qd  = ln >> 4;
    const int l15 = ln & 15;

    int cq[4], nbq[4], total = 0;
    #pragma unroll
    for (int q = 0; q < 4; ++q) {
        int c = cnt[q]; if (c > CAP1Q) c = CAP1Q;
        cq[q] = c; nbq[q] = (c + 15) >> 4; total += nbq[q];
    }

    for (int j = blockIdx.x; j < total; j += gridDim.x) {
        int rem = j, q = 0;
        while (rem >= nbq[q]) { rem -= nbq[q]; ++q; }
        const int base = rem << 4;

        if (tid < 16) {
            int idx = base + tid;
            int tok = list[q * CAP1Q + (idx < cq[q] ? idx : base)];   // pad = dup
            stok[tid] = tok;
            scnt[tid] = 0;
            sv1[tid]  = fmaxf(part[tok].x, part[TT + tok].x);         // merged fp16 max
        }
        __syncthreads();

        // A-fragments for the item's 16 tokens (identical construction to gemm;
        // all waves build the same fragments)
        f16x8 ah[8];
        {
            const int tok = stok[l15];
            const float sxv = sxa[tok];
            const float* xr = x + (size_t)tok * Dq + qd * 8;
            #pragma unroll
            for (int ch = 0; ch < 8; ++ch) {
                float4 u = *(const float4*)(xr + ch * 32);
                float4 v = *(const float4*)(xr + ch * 32 + 4);
                f16x8 f;
                f[0] = (_Float16)(u.x * sxv); f[1] = (_Float16)(u.y * sxv);
                f[2] = (_Float16)(u.z * sxv); f[3] = (_Float16)(u.w * sxv);
                f[4] = (_Float16)(v.x * sxv); f[5] = (_Float16)(v.y * sxv);
                f[6] = (_Float16)(v.z * sxv); f[7] = (_Float16)(v.w * sxv);
                ah[ch] = f;
            }
        }
        float thr[4];
        #pragma unroll
        for (int r = 0; r < 4; ++r) thr[r] = sv1[qd * 4 + r] - THRESH;

        // scan: wave wv covers tiles [wv*16, wv*16+16) = codebook quarter wv
        const char* qbase = enh + ((size_t)(q * 64)) * 16384;
        for (int tt = 0; tt < 16; ++tt) {
            const int T = wv * 16 + tt;
            const char* tb = qbase + (size_t)T * 16384;
            #pragma unroll
            for (int s = 0; s < 2; ++s) {
                const int  c  = s * 16 + l15;
                const char* cb = tb + c * 512;
                f16x8 bfr[8];
                #pragma unroll
                for (int ch = 0; ch < 8; ++ch)
                    bfr[ch] = *(const f16x8*)(cb + ((((ch << 2) | qd) ^ c) << 4));

                f32x4 a = {0.f, 0.f, 0.f, 0.f};
                #pragma unroll
                for (int ch = 0; ch < 8; ++ch)
                    a = __builtin_amdgcn_mfma_f32_16x16x32_f16(ah[ch], bfr[ch], a, 0, 0, 0);

                const int cg = (T << 5) | (s << 4) | l15;   // global code 0..2047
                #pragma unroll
                for (int r = 0; r < 4; ++r) {
                    if (a[r] >= thr[r]) {
                        int slot = qd * 4 + r;               // token slot 0..15
                        int pos = atomicAdd(&scnt[slot], 1);
                        if (pos < CAND_MAX) scand[slot][pos] = (unsigned short)cg;
                    }
                }
            }
        }
        __syncthreads();

        // stage numpy-normalized x rows (wave handles 4 rows; fix_partial-exact)
        for (int rr = 0; rr < 4; ++rr) {
            int i = wv * 4 + rr;
            const float* xr = x + (size_t)stok[i] * Dq;
            float nm = np_norm_wave(xr, ln);
            #pragma unroll
            for (int e = 0; e < 4; ++e)
                xn[i][ln * 4 + e] = f32_div(xr[ln * 4 + e], nm);
        }
        __syncthreads();

        // parallel exact eval: token i = tid>>4, candidate slot sl = tid&15
        {
            const int i = tid >> 4, sl = tid & 15;
            const int nc = scnt[i];
            float bs = -2.0f; int bc = 0x7fffffff;
            if (nc <= CAND_MAX && sl < nc) {
                int code = scand[i][sl];
                const float* er2 = enp + ((size_t)(q * Kq + code)) * Dq;
                float l0 = 0.f, l1 = 0.f, l2 = 0.f, l3 = 0.f;
                for (int d = 0; d < Dq; d += 4) {
                    float4 e = *(const float4*)(er2 + d);
                    float4 xv = *(const float4*)&xn[i][d];
                    l0 = l0 + xv.x * e.x; l1 = l1 + xv.y * e.y;
                    l2 = l2 + xv.z * e.z; l3 = l3 + xv.w * e.w;
                }
                bs = (l0 + l1) + (l2 + l3);   // numpy SSE tree
                bc = code;
            }
            sc_s[tid] = bs; sc_c[tid] = bc;
        }
        __syncthreads();
        if (tid < 16) {
            float bs = sc_s[tid * 16]; int bc = sc_c[tid * 16];
            #pragma unroll
            for (int sl = 1; sl < 16; ++sl) {
                float os = sc_s[tid * 16 + sl]; int oc = sc_c[tid * 16 + sl];
                if (os > bs || (os == bs && oc < bc)) { bs = os; bc = oc; }
            }
            fbc[tid] = bc;
        }
        __syncthreads();

        // overflow fallback: exact full scan (block-uniform branch; ~never)
        for (int i = 0; i < 16; ++i) {
            if (scnt[i] > CAND_MAX) {
                float bs = -2.0f; int bc = 0x7fffffff;
                for (int k = 0; k < 8; ++k) {
                    int code = k * 256 + tid;
                    const float* er2 = enp + ((size_t)(q * Kq + code)) * Dq;
                    float l0 = 0.f, l1 = 0.f, l2 = 0.f, l3 = 0.f;
                    for (int d = 0; d < Dq; d += 4) {
                        float4 e = *(const float4*)(er2 + d);
                        float4 xv = *(const float4*)&xn[i][d];
                        l0 = l0 + xv.x * e.x; l1 = l1 + xv.y * e.y;
                        l2 = l2 + xv.z * e.z; l3 = l3 + xv.w * e.w;
                    }
                    float sE = (l0 + l1) + (l2 + l3);
                    if (sE > bs || (sE == bs && code < bc)) { bs = sE; bc = code; }
                }
                sc_s[tid] = bs; sc_c[tid] = bc;
                __syncthreads();
                if (tid == 0) {
                    for (int t2 = 1; t2 < 256; ++t2) {
                        float os = sc_s[t2]; int oc = sc_c[t2];
                        if (os > bs || (os == bs && oc < bc)) { bs = os; bc = oc; }
                    }
                    fbc[i] = bc;
                }
                __syncthreads();
            }
        }

        // write encoding + quantized rows (wave writes 4 rows)
        for (int rr = 0; rr < 4; ++rr) {
            const int i = wv * 4 + rr;
            const int tok = stok[i];
            const int bc = fbc[i];
            if (ln == 0) out[QUANT_ELEMS + (size_t)tok] = (float)bc;
            const float* er = embed + ((size_t)(q * Kq + bc)) * Dq;
            float4 v = *(const float4*)(er + ln * 4);
            *(float4*)(out + (size_t)tok * Dq + ln * 4) = v;
        }
        __syncthreads();   // shared reuse next item
    }
}

extern "C" void kernel_launch(void* const* d_in, const int* in_sizes, int n_in,
                              void* d_out, int out_size, void* d_ws, size_t ws_size,
                              hipStream_t stream) {
    const float* x     = (const float*)d_in[0];
    const float* embed = (const float*)d_in[1];
    float* out = (float*)d_out;
    char*  ws  = (char*)d_ws;
    int*    cnt    = (int*)(ws + WS_CNT_OFF);
    int*    list   = (int*)(ws + WS_LIST_OFF);
    float*  sxa    = (float*)(ws + WS_SX_OFF);
    char*   enh    = ws + WS_ENH_OFF;
    float*  enp    = (float*)(ws + WS_ENP_OFF);
    float4* part   = (float4*)(ws + WS_PART_OFF);

    prep_kernel<<<3072, 256, 0, stream>>>(embed, x, enh, enp, sxa, cnt, out);
    gemm_kernel<<<512, 256, 0, stream>>>(x, sxa, enh, part);
    merge_kernel<<<2048, 256, 0, stream>>>(embed, part, out, cnt, list);
    cand_kernel<<<1024, 256, 0, stream>>>(x, sxa, enh, enp, part, embed, cnt, list, out);
}